// Round 2
// baseline (3007.702 us; speedup 1.0000x reference)
//
#include <hip/hip_runtime.h>

#define NB 2
#define NP 8192
#define D 64
#define KNN 16

__device__ __forceinline__ float bcast(float v, int lane) {
  return __uint_as_float((unsigned int)__builtin_amdgcn_readlane((int)__float_as_uint(v), lane));
}

// load a 64-element f32 row into 64 registers (16x dwordx4)
__device__ __forceinline__ void load_row64(const float* __restrict__ p, float (&w)[64]) {
  const float4* q = reinterpret_cast<const float4*>(p);
  #pragma unroll
  for (int i = 0; i < 16; ++i) {
    float4 v = q[i];
    w[i*4+0] = v.x; w[i*4+1] = v.y; w[i*4+2] = v.z; w[i*4+3] = v.w;
  }
}

// y[l] = sum_c w[c] * x_broadcast_from_lane_c   (all 64 lanes active)
__device__ __forceinline__ float matvec64(const float (&w)[64], float x) {
  float a0 = 0.f, a1 = 0.f, a2 = 0.f, a3 = 0.f;
  #pragma unroll
  for (int c = 0; c < 64; c += 4) {
    a0 = fmaf(w[c+0], bcast(x, c+0), a0);
    a1 = fmaf(w[c+1], bcast(x, c+1), a1);
    a2 = fmaf(w[c+2], bcast(x, c+2), a2);
    a3 = fmaf(w[c+3], bcast(x, c+3), a3);
  }
  return (a0 + a1) + (a2 + a3);
}

// ---------------- per-point feature transforms: phi, psi, alpha ----------------
__global__ void __launch_bounds__(256)
k_transform(const float* __restrict__ feat,
            const float* __restrict__ W1,   const float* __restrict__ b1,
            const float* __restrict__ Wphi, const float* __restrict__ bphi,
            const float* __restrict__ Wpsi, const float* __restrict__ bpsi,
            const float* __restrict__ Wal,  const float* __restrict__ bal,
            float* __restrict__ phi, float* __restrict__ psi, float* __restrict__ al)
{
  const int wid = (blockIdx.x * 256 + threadIdx.x) >> 6;   // point index in [0, NB*NP)
  const int l   = threadIdx.x & 63;                        // channel
  const size_t po = (size_t)wid * D;

  float fin = feat[po + l];
  float w[64];

  load_row64(W1 + l * D, w);
  float f  = b1[l]   + matvec64(w, fin);
  load_row64(Wphi + l * D, w);
  float ph = bphi[l] + matvec64(w, f);
  load_row64(Wpsi + l * D, w);
  float ps = bpsi[l] + matvec64(w, f);
  load_row64(Wal + l * D, w);
  float av = bal[l]  + matvec64(w, f);

  phi[po + l] = ph;
  psi[po + l] = ps;
  al [po + l] = av;
}

// ---------------- exact KNN (matches reference arithmetic) ----------------
__global__ void __launch_bounds__(64)
k_knn(const float* __restrict__ xyz, int* __restrict__ knn_idx)
{
  __shared__ float4 tile[1024];
  const int q = blockIdx.x * 64 + threadIdx.x;   // global query
  const int b = q >> 13;
  const int i = q & (NP - 1);
  const float* base = xyz + (size_t)b * NP * 3;

  const float xi = base[i*3+0];
  const float yi = base[i*3+1];
  const float zi = base[i*3+2];
  const float sqi = __fadd_rn(__fadd_rn(__fmul_rn(xi,xi), __fmul_rn(yi,yi)), __fmul_rn(zi,zi));

  float hd[KNN], hq[KNN]; int hix[KNN];
  #pragma unroll
  for (int s = 0; s < KNN; ++s) { hd[s] = 3.0e38f; hq[s] = 3.0e38f; hix[s] = 0; }

  for (int t0 = 0; t0 < NP; t0 += 1024) {
    __syncthreads();
    #pragma unroll
    for (int c = 0; c < 16; ++c) {
      int j = t0 + c * 64 + threadIdx.x;
      float x = base[j*3+0];
      float y = base[j*3+1];
      float z = base[j*3+2];
      float sq = __fadd_rn(__fadd_rn(__fmul_rn(x,x), __fmul_rn(y,y)), __fmul_rn(z,z));
      tile[c*64 + threadIdx.x] = make_float4(x, y, z, sq);
    }
    __syncthreads();
    for (int c = 0; c < 1024; ++c) {
      float4 p = tile[c];
      float dot = __fadd_rn(__fadd_rn(__fmul_rn(xi,p.x), __fmul_rn(yi,p.y)), __fmul_rn(zi,p.z));
      float d2  = __fsub_rn(__fadd_rn(sqi, p.w), __fmul_rn(2.0f, dot));
      if (d2 < hq[KNN-1]) {                       // monotone pre-filter (no sqrt on common path)
        float ds = __fsqrt_rn(fmaxf(d2, 0.0f));
        if (ds < hd[KNN-1]) {                     // strict: ties keep lower index (scan order)
          float cd = ds, cq = d2; int ci = t0 + c;
          #pragma unroll
          for (int s = 0; s < KNN; ++s) {
            if (cd < hd[s]) {
              float td = hd[s]; hd[s] = cd; cd = td;
              float tq = hq[s]; hq[s] = cq; cq = tq;
              int   ti = hix[s]; hix[s] = ci; ci = ti;
            }
          }
        }
      }
    }
  }
  #pragma unroll
  for (int s = 0; s < KNN; ++s) knn_idx[(size_t)q * KNN + s] = hix[s];
}

// ---------------- main per-pair kernel: one wave per point ----------------
__global__ void __launch_bounds__(256)
k_main(const float* __restrict__ xyz,
       const float* __restrict__ feat,
       const int* __restrict__ knn_idx,
       const float* __restrict__ phi, const float* __restrict__ psi, const float* __restrict__ al,
       const float* __restrict__ Wd1, const float* __restrict__ bd1,
       const float* __restrict__ Wd2, const float* __restrict__ bd2,
       const float* __restrict__ Wg,  const float* __restrict__ bg,
       const float* __restrict__ W2,  const float* __restrict__ b2,
       float* __restrict__ out)
{
  const int wid = (blockIdx.x * 256 + threadIdx.x) >> 6;   // point index
  const int l   = threadIdx.x & 63;                        // channel
  const int b   = wid >> 13;
  const int i   = wid & (NP - 1);
  const float* xb = xyz + (size_t)b * NP * 3;

  const float xi = xb[i*3+0];
  const float yi = xb[i*3+1];
  const float zi = xb[i*3+2];

  const float wd1x = Wd1[l*3+0];
  const float wd1y = Wd1[l*3+1];
  const float wd1z = Wd1[l*3+2];
  const float bd1l = bd1[l];
  const float bd2l = bd2[l];
  const float bgl  = bg[l];

  float wd2[64]; load_row64(Wd2 + l * D, wd2);
  float wg [64]; load_row64(Wg  + l * D, wg);

  const size_t po = (size_t)wid * D;
  const float phil = phi[po + l];
  const int* ki = knn_idx + (size_t)wid * KNN;

  float acc = 0.f;
  #pragma unroll 1
  for (int kk = 0; kk < KNN; ++kk) {
    int j = ki[kk];
    float dx = xi - xb[j*3+0];
    float dy = yi - xb[j*3+1];
    float dz = zi - xb[j*3+2];

    // delta = relu((diff @ Wd1^T + bd1) @ Wd2^T + bd2)
    float t = fmaf(wd1z, dz, fmaf(wd1y, dy, fmaf(wd1x, dx, bd1l)));
    float h = bd2l + matvec64(wd2, t);
    float delta = fmaxf(h, 0.f);

    size_t jo = ((size_t)(b * NP + j)) * D + l;
    float psij = psi[jo];
    float alj  = al [jo];

    float beta = phil - psij + delta;
    float gam  = bgl + matvec64(wg, beta);

    // softmax over the 64 channels (lanes)
    float m = gam;
    #pragma unroll
    for (int s = 32; s >= 1; s >>= 1) m = fmaxf(m, __shfl_xor(m, s, 64));
    float e = __expf(gam - m);
    float ssum = e;
    #pragma unroll
    for (int s = 32; s >= 1; s >>= 1) ssum += __shfl_xor(ssum, s, 64);
    float rho = e / ssum;

    acc = fmaf(rho, alj + delta, acc);
  }

  // out = acc @ W2^T + b2 + feat  (residual), store f32
  float w2r[64]; load_row64(W2 + l * D, w2r);
  out[po + l] = b2[l] + matvec64(w2r, acc) + feat[po + l];
}

extern "C" void kernel_launch(void* const* d_in, const int* in_sizes, int n_in,
                              void* d_out, int out_size, void* d_ws, size_t ws_size,
                              hipStream_t stream) {
  const float* xyz  = (const float*)d_in[0];
  const float* feat = (const float*)d_in[1];
  // d_in[2] = k (int32) == 16, compile-time constant here
  const float* W1   = (const float*)d_in[3];
  const float* b1   = (const float*)d_in[4];
  const float* Wphi = (const float*)d_in[5];
  const float* bphi = (const float*)d_in[6];
  const float* Wpsi = (const float*)d_in[7];
  const float* bpsi = (const float*)d_in[8];
  const float* Wal  = (const float*)d_in[9];
  const float* bal  = (const float*)d_in[10];
  const float* Wg   = (const float*)d_in[11];
  const float* bg   = (const float*)d_in[12];
  const float* Wd1  = (const float*)d_in[13];
  const float* bd1  = (const float*)d_in[14];
  const float* Wd2  = (const float*)d_in[15];
  const float* bd2  = (const float*)d_in[16];
  const float* W2   = (const float*)d_in[17];
  const float* b2   = (const float*)d_in[18];

  float* out = (float*)d_out;

  // workspace layout (f32): phi | psi | al | knn_idx  (~13 MiB)
  float* phi = (float*)d_ws;
  float* psi = phi + (size_t)NB * NP * D;
  float* al  = psi + (size_t)NB * NP * D;
  int* knn_idx = (int*)(al + (size_t)NB * NP * D);

  // output 0: points_xyz passthrough (f32)
  hipMemcpyAsync(d_out, d_in[0], (size_t)NB * NP * 3 * sizeof(float),
                 hipMemcpyDeviceToDevice, stream);

  k_transform<<<NB * NP * 64 / 256, 256, 0, stream>>>(feat, W1, b1, Wphi, bphi,
                                                      Wpsi, bpsi, Wal, bal, phi, psi, al);
  k_knn<<<NB * NP / 64, 64, 0, stream>>>(xyz, knn_idx);
  k_main<<<NB * NP * 64 / 256, 256, 0, stream>>>(xyz, feat, knn_idx, phi, psi, al,
                                                 Wd1, bd1, Wd2, bd2, Wg, bg, W2, b2,
                                                 out + (size_t)NB * NP * 3);
}

// Round 3
// 900.173 us; speedup vs baseline: 3.3412x; 3.3412x over previous
//
#include <hip/hip_runtime.h>

#define NB 2
#define NP 8192
#define D 64
#define KNN 16

__device__ __forceinline__ float bcast(float v, int lane) {
  return __uint_as_float((unsigned int)__builtin_amdgcn_readlane((int)__float_as_uint(v), lane));
}

// load a 64-element f32 row into 64 registers (16x dwordx4)
__device__ __forceinline__ void load_row64(const float* __restrict__ p, float (&w)[64]) {
  const float4* q = reinterpret_cast<const float4*>(p);
  #pragma unroll
  for (int i = 0; i < 16; ++i) {
    float4 v = q[i];
    w[i*4+0] = v.x; w[i*4+1] = v.y; w[i*4+2] = v.z; w[i*4+3] = v.w;
  }
}

// y[l] = sum_c w[c] * x_broadcast_from_lane_c   (all 64 lanes active)
__device__ __forceinline__ float matvec64(const float (&w)[64], float x) {
  float a0 = 0.f, a1 = 0.f, a2 = 0.f, a3 = 0.f;
  #pragma unroll
  for (int c = 0; c < 64; c += 4) {
    a0 = fmaf(w[c+0], bcast(x, c+0), a0);
    a1 = fmaf(w[c+1], bcast(x, c+1), a1);
    a2 = fmaf(w[c+2], bcast(x, c+2), a2);
    a3 = fmaf(w[c+3], bcast(x, c+3), a3);
  }
  return (a0 + a1) + (a2 + a3);
}

// ---------------- per-point feature transforms: phi, psi, alpha ----------------
__global__ void __launch_bounds__(256)
k_transform(const float* __restrict__ feat,
            const float* __restrict__ W1,   const float* __restrict__ b1,
            const float* __restrict__ Wphi, const float* __restrict__ bphi,
            const float* __restrict__ Wpsi, const float* __restrict__ bpsi,
            const float* __restrict__ Wal,  const float* __restrict__ bal,
            float* __restrict__ phi, float* __restrict__ psi, float* __restrict__ al)
{
  const int wid = (blockIdx.x * 256 + threadIdx.x) >> 6;   // point index in [0, NB*NP)
  const int l   = threadIdx.x & 63;                        // channel
  const size_t po = (size_t)wid * D;

  float fin = feat[po + l];
  float w[64];

  load_row64(W1 + l * D, w);
  float f  = b1[l]   + matvec64(w, fin);
  load_row64(Wphi + l * D, w);
  float ph = bphi[l] + matvec64(w, f);
  load_row64(Wpsi + l * D, w);
  float ps = bpsi[l] + matvec64(w, f);
  load_row64(Wal + l * D, w);
  float av = bal[l]  + matvec64(w, f);

  phi[po + l] = ph;
  psi[po + l] = ps;
  al [po + l] = av;
}

// ---------------- prep: pack (x, y, z, |p|^2) per point ----------------
__global__ void __launch_bounds__(256)
k_prep(const float* __restrict__ xyz, float4* __restrict__ pts4)
{
  const int t = blockIdx.x * 256 + threadIdx.x;   // 0 .. NB*NP-1
  const float x = xyz[t*3+0];
  const float y = xyz[t*3+1];
  const float z = xyz[t*3+2];
  const float sq = __fadd_rn(__fadd_rn(__fmul_rn(x,x), __fmul_rn(y,y)), __fmul_rn(z,z));
  pts4[t] = make_float4(x, y, z, sq);
}

// ---------------- KNN v2: one wave per query, lanes split candidates ----------------
// key = (bits(sqrt(d2)) << 16) | candidate_idx  -> exact (distance, index) order.
__global__ void __launch_bounds__(256)
k_knn2(const float4* __restrict__ pts4, int* __restrict__ knn_idx)
{
  const int q    = (blockIdx.x * 256 + threadIdx.x) >> 6;  // global query id
  const int lane = threadIdx.x & 63;
  const int b    = q >> 13;
  const float4* pb = pts4 + (size_t)b * NP;

  const float4 qp = pb[q & (NP - 1)];          // uniform per wave -> scalar load
  const float xi = qp.x, yi = qp.y, zi = qp.z, sqi = qp.w;

  unsigned long long key[KNN];
  #pragma unroll
  for (int s = 0; s < KNN; ++s) key[s] = ~0ull;

  unsigned long long thr = ~0ull;              // wave-shared upper bound on final 16th

  #pragma unroll 1
  for (int c0 = 0; c0 < NP / 64; c0 += 16) {
    #pragma unroll
    for (int cc = 0; cc < 16; ++cc) {
      const int j = (c0 + cc) * 64 + lane;     // coalesced across lanes
      float4 p = pb[j];
      float dot = __fadd_rn(__fadd_rn(__fmul_rn(xi,p.x), __fmul_rn(yi,p.y)), __fmul_rn(zi,p.z));
      float d2  = __fsub_rn(__fadd_rn(sqi, p.w), __fmul_rn(2.0f, dot));
      float ds  = __fsqrt_rn(fmaxf(d2, 0.0f));
      unsigned long long kc =
          (((unsigned long long)__float_as_uint(ds)) << 16) | (unsigned)j;
      unsigned long long lim = key[KNN-1] < thr ? key[KNN-1] : thr;
      if (kc < lim) {                          // bubble-insert, keeps ascending order
        unsigned long long cur = kc;
        #pragma unroll
        for (int s = 0; s < KNN; ++s) {
          unsigned long long ks = key[s];
          bool lt = cur < ks;
          key[s] = lt ? cur : ks;
          cur    = lt ? ks  : cur;
        }
      }
    }
    // refresh shared threshold: min over lanes of local 16th
    unsigned long long m = key[KNN-1];
    #pragma unroll
    for (int s = 32; s >= 1; s >>= 1) {
      unsigned long long o = __shfl_xor(m, s, 64);
      m = o < m ? o : m;
    }
    thr = m;
  }

  // in-wave merge: extract global top-16 from 64 sorted lists
  int myout = 0;
  #pragma unroll
  for (int r = 0; r < KNN; ++r) {
    unsigned long long m = key[0];
    #pragma unroll
    for (int s = 32; s >= 1; s >>= 1) {
      unsigned long long o = __shfl_xor(m, s, 64);
      m = o < m ? o : m;
    }
    if (lane == r) myout = (int)(m & 0xffffu);
    const bool win = (key[0] == m);            // keys unique -> exactly one winner
    #pragma unroll
    for (int s = 0; s < KNN - 1; ++s) key[s] = win ? key[s+1] : key[s];
    key[KNN-1] = win ? ~0ull : key[KNN-1];
  }
  if (lane < KNN) knn_idx[(size_t)q * KNN + lane] = myout;
}

// ---------------- main per-pair kernel: one wave per point ----------------
__global__ void __launch_bounds__(256)
k_main(const float* __restrict__ xyz,
       const float* __restrict__ feat,
       const int* __restrict__ knn_idx,
       const float* __restrict__ phi, const float* __restrict__ psi, const float* __restrict__ al,
       const float* __restrict__ Wd1, const float* __restrict__ bd1,
       const float* __restrict__ Wd2, const float* __restrict__ bd2,
       const float* __restrict__ Wg,  const float* __restrict__ bg,
       const float* __restrict__ W2,  const float* __restrict__ b2,
       float* __restrict__ out)
{
  const int wid = (blockIdx.x * 256 + threadIdx.x) >> 6;   // point index
  const int l   = threadIdx.x & 63;                        // channel
  const int b   = wid >> 13;
  const int i   = wid & (NP - 1);
  const float* xb = xyz + (size_t)b * NP * 3;

  const float xi = xb[i*3+0];
  const float yi = xb[i*3+1];
  const float zi = xb[i*3+2];

  const float wd1x = Wd1[l*3+0];
  const float wd1y = Wd1[l*3+1];
  const float wd1z = Wd1[l*3+2];
  const float bd1l = bd1[l];
  const float bd2l = bd2[l];
  const float bgl  = bg[l];

  float wd2[64]; load_row64(Wd2 + l * D, wd2);
  float wg [64]; load_row64(Wg  + l * D, wg);

  const size_t po = (size_t)wid * D;
  const float phil = phi[po + l];
  const int* ki = knn_idx + (size_t)wid * KNN;

  float acc = 0.f;
  #pragma unroll 1
  for (int kk = 0; kk < KNN; ++kk) {
    int j = ki[kk];
    float dx = xi - xb[j*3+0];
    float dy = yi - xb[j*3+1];
    float dz = zi - xb[j*3+2];

    // delta = relu((diff @ Wd1^T + bd1) @ Wd2^T + bd2)
    float t = fmaf(wd1z, dz, fmaf(wd1y, dy, fmaf(wd1x, dx, bd1l)));
    float h = bd2l + matvec64(wd2, t);
    float delta = fmaxf(h, 0.f);

    size_t jo = ((size_t)(b * NP + j)) * D + l;
    float psij = psi[jo];
    float alj  = al [jo];

    float beta = phil - psij + delta;
    float gam  = bgl + matvec64(wg, beta);

    // softmax over the 64 channels (lanes)
    float m = gam;
    #pragma unroll
    for (int s = 32; s >= 1; s >>= 1) m = fmaxf(m, __shfl_xor(m, s, 64));
    float e = __expf(gam - m);
    float ssum = e;
    #pragma unroll
    for (int s = 32; s >= 1; s >>= 1) ssum += __shfl_xor(ssum, s, 64);
    float rho = e / ssum;

    acc = fmaf(rho, alj + delta, acc);
  }

  // out = acc @ W2^T + b2 + feat  (residual), store f32
  float w2r[64]; load_row64(W2 + l * D, w2r);
  out[po + l] = b2[l] + matvec64(w2r, acc) + feat[po + l];
}

extern "C" void kernel_launch(void* const* d_in, const int* in_sizes, int n_in,
                              void* d_out, int out_size, void* d_ws, size_t ws_size,
                              hipStream_t stream) {
  const float* xyz  = (const float*)d_in[0];
  const float* feat = (const float*)d_in[1];
  // d_in[2] = k (int32) == 16, compile-time constant here
  const float* W1   = (const float*)d_in[3];
  const float* b1   = (const float*)d_in[4];
  const float* Wphi = (const float*)d_in[5];
  const float* bphi = (const float*)d_in[6];
  const float* Wpsi = (const float*)d_in[7];
  const float* bpsi = (const float*)d_in[8];
  const float* Wal  = (const float*)d_in[9];
  const float* bal  = (const float*)d_in[10];
  const float* Wg   = (const float*)d_in[11];
  const float* bg   = (const float*)d_in[12];
  const float* Wd1  = (const float*)d_in[13];
  const float* bd1  = (const float*)d_in[14];
  const float* Wd2  = (const float*)d_in[15];
  const float* bd2  = (const float*)d_in[16];
  const float* W2   = (const float*)d_in[17];
  const float* b2   = (const float*)d_in[18];

  float* out = (float*)d_out;

  // workspace layout (f32): phi | psi | al | knn_idx | pts4  (~14 MiB)
  float* phi = (float*)d_ws;
  float* psi = phi + (size_t)NB * NP * D;
  float* al  = psi + (size_t)NB * NP * D;
  int* knn_idx = (int*)(al + (size_t)NB * NP * D);
  float4* pts4 = (float4*)(knn_idx + (size_t)NB * NP * KNN);

  // output 0: points_xyz passthrough (f32)
  hipMemcpyAsync(d_out, d_in[0], (size_t)NB * NP * 3 * sizeof(float),
                 hipMemcpyDeviceToDevice, stream);

  k_prep<<<NB * NP / 256, 256, 0, stream>>>(xyz, pts4);
  k_transform<<<NB * NP * 64 / 256, 256, 0, stream>>>(feat, W1, b1, Wphi, bphi,
                                                      Wpsi, bpsi, Wal, bal, phi, psi, al);
  k_knn2<<<NB * NP / 4, 256, 0, stream>>>(pts4, knn_idx);
  k_main<<<NB * NP * 64 / 256, 256, 0, stream>>>(xyz, feat, knn_idx, phi, psi, al,
                                                 Wd1, bd1, Wd2, bd2, Wg, bg, W2, b2,
                                                 out + (size_t)NB * NP * 3);
}

// Round 4
// 541.943 us; speedup vs baseline: 5.5499x; 1.6610x over previous
//
#include <hip/hip_runtime.h>

#define NB 2
#define NP 8192
#define D 64
#define KNN 16

__device__ __forceinline__ float bcast(float v, int lane) {
  return __uint_as_float((unsigned int)__builtin_amdgcn_readlane((int)__float_as_uint(v), lane));
}

// load a 64-element f32 row into 64 registers (16x dwordx4)
__device__ __forceinline__ void load_row64(const float* __restrict__ p, float (&w)[64]) {
  const float4* q = reinterpret_cast<const float4*>(p);
  #pragma unroll
  for (int i = 0; i < 16; ++i) {
    float4 v = q[i];
    w[i*4+0] = v.x; w[i*4+1] = v.y; w[i*4+2] = v.z; w[i*4+3] = v.w;
  }
}

// y[l] = sum_c w[c] * x_broadcast_from_lane_c   (all 64 lanes active)
__device__ __forceinline__ float matvec64(const float (&w)[64], float x) {
  float a0 = 0.f, a1 = 0.f, a2 = 0.f, a3 = 0.f;
  #pragma unroll
  for (int c = 0; c < 64; c += 4) {
    a0 = fmaf(w[c+0], bcast(x, c+0), a0);
    a1 = fmaf(w[c+1], bcast(x, c+1), a1);
    a2 = fmaf(w[c+2], bcast(x, c+2), a2);
    a3 = fmaf(w[c+3], bcast(x, c+3), a3);
  }
  return (a0 + a1) + (a2 + a3);
}

// ---------------- per-point feature transforms: phi, psi, alpha ----------------
__global__ void __launch_bounds__(256)
k_transform(const float* __restrict__ feat,
            const float* __restrict__ W1,   const float* __restrict__ b1,
            const float* __restrict__ Wphi, const float* __restrict__ bphi,
            const float* __restrict__ Wpsi, const float* __restrict__ bpsi,
            const float* __restrict__ Wal,  const float* __restrict__ bal,
            float* __restrict__ phi, float* __restrict__ psi, float* __restrict__ al)
{
  const int wid = (blockIdx.x * 256 + threadIdx.x) >> 6;   // point index in [0, NB*NP)
  const int l   = threadIdx.x & 63;                        // channel
  const size_t po = (size_t)wid * D;

  float fin = feat[po + l];
  float w[64];

  load_row64(W1 + l * D, w);
  float f  = b1[l]   + matvec64(w, fin);
  load_row64(Wphi + l * D, w);
  float ph = bphi[l] + matvec64(w, f);
  load_row64(Wpsi + l * D, w);
  float ps = bpsi[l] + matvec64(w, f);
  load_row64(Wal + l * D, w);
  float av = bal[l]  + matvec64(w, f);

  phi[po + l] = ph;
  psi[po + l] = ps;
  al [po + l] = av;
}

// ---------------- prep: pack (x, y, z, |p|^2) per point ----------------
__global__ void __launch_bounds__(256)
k_prep(const float* __restrict__ xyz, float4* __restrict__ pts4)
{
  const int t = blockIdx.x * 256 + threadIdx.x;   // 0 .. NB*NP-1
  const float x = xyz[t*3+0];
  const float y = xyz[t*3+1];
  const float z = xyz[t*3+2];
  const float sq = __fadd_rn(__fadd_rn(__fmul_rn(x,x), __fmul_rn(y,y)), __fmul_rn(z,z));
  pts4[t] = make_float4(x, y, z, sq);
}

// ---------------- KNN v3: wave-distributed exact top-16, d2 prefilter ----------------
// Lanes 0..15 hold the running global top-16 as ascending u64 keys
// key = (bits(sqrt(d2)) << 16) | idx  (exact (distance, index) order).
__global__ void __launch_bounds__(256)
k_knn3(const float4* __restrict__ pts4, int* __restrict__ knn_idx)
{
  const int q    = (blockIdx.x * 256 + threadIdx.x) >> 6;  // global query id
  const int lane = threadIdx.x & 63;
  const int b    = q >> 13;
  const float4* pb = pts4 + (size_t)b * NP;

  const float4 qp = pb[q & (NP - 1)];          // uniform per wave -> scalar load
  const float xi = qp.x, yi = qp.y, zi = qp.z, sqi = qp.w;

  // ---- init: candidates 0..63, one per lane; full bitonic sort across lanes ----
  unsigned long long key;
  {
    float4 p = pb[lane];
    float dot = __fadd_rn(__fadd_rn(__fmul_rn(xi,p.x), __fmul_rn(yi,p.y)), __fmul_rn(zi,p.z));
    float d2  = __fsub_rn(__fadd_rn(sqi, p.w), __fmul_rn(2.0f, dot));
    float ds  = __fsqrt_rn(fmaxf(d2, 0.0f));
    key = (((unsigned long long)__float_as_uint(ds)) << 16) | (unsigned)lane;
  }
  #pragma unroll
  for (int k = 2; k <= 64; k <<= 1) {
    #pragma unroll
    for (int j = k >> 1; j >= 1; j >>= 1) {
      unsigned long long other = __shfl_xor(key, j, 64);
      const bool up    = (lane & k) == 0;        // ascending block (k=64: all)
      const bool lower = (lane & j) == 0;
      const bool takemin = (lower == up);
      const bool omin = other < key;
      key = (takemin == omin) ? other : key;
    }
  }
  // lanes 0..15: 16 smallest ascending; park +inf elsewhere
  if (lane >= KNN) key = ~0ull;

  float thr_d2;
  {
    float ds16 = __uint_as_float((unsigned int)(__shfl(key, KNN - 1, 64) >> 16));
    thr_d2 = __fmul_rn(__fmul_rn(ds16, ds16), 1.000001f);   // safe over-approx
  }

  // ---- main scan: batches of 64 candidates ----
  #pragma unroll 1
  for (int c = 1; c < NP / 64; ++c) {
    const int j = c * 64 + lane;
    float4 p = pb[j];
    float dot = __fadd_rn(__fadd_rn(__fmul_rn(xi,p.x), __fmul_rn(yi,p.y)), __fmul_rn(zi,p.z));
    float d2  = __fsub_rn(__fadd_rn(sqi, p.w), __fmul_rn(2.0f, dot));

    unsigned long long mask = __ballot(d2 <= thr_d2);
    if (mask) {
      float ds = __fsqrt_rn(fmaxf(d2, 0.0f));
      unsigned long long kc =
          (((unsigned long long)__float_as_uint(ds)) << 16) | (unsigned)j;
      do {
        const int src = __ffsll((long long)mask) - 1;
        mask &= mask - 1;
        const unsigned long long kin = __shfl(kc, src, 64);
        const int pos = __popcll(__ballot((lane < KNN) && (key < kin)));
        if (pos < KNN) {                          // else kin >= current 16th: skip
          unsigned long long up = __shfl_up(key, 1, 64);
          unsigned long long nk = (lane < pos) ? key : (lane == pos ? kin : up);
          if (lane < KNN) key = nk;
          float ds16 = __uint_as_float((unsigned int)(__shfl(key, KNN - 1, 64) >> 16));
          thr_d2 = __fmul_rn(__fmul_rn(ds16, ds16), 1.000001f);
        }
      } while (mask);
    }
  }

  if (lane < KNN) knn_idx[(size_t)q * KNN + lane] = (int)(key & 0xffffu);
}

// ---------------- main per-pair kernel: one wave per point ----------------
__global__ void __launch_bounds__(256)
k_main(const float* __restrict__ xyz,
       const float* __restrict__ feat,
       const int* __restrict__ knn_idx,
       const float* __restrict__ phi, const float* __restrict__ psi, const float* __restrict__ al,
       const float* __restrict__ Wd1, const float* __restrict__ bd1,
       const float* __restrict__ Wd2, const float* __restrict__ bd2,
       const float* __restrict__ Wg,  const float* __restrict__ bg,
       const float* __restrict__ W2,  const float* __restrict__ b2,
       float* __restrict__ out)
{
  const int wid = (blockIdx.x * 256 + threadIdx.x) >> 6;   // point index
  const int l   = threadIdx.x & 63;                        // channel
  const int b   = wid >> 13;
  const int i   = wid & (NP - 1);
  const float* xb = xyz + (size_t)b * NP * 3;

  const float xi = xb[i*3+0];
  const float yi = xb[i*3+1];
  const float zi = xb[i*3+2];

  const float wd1x = Wd1[l*3+0];
  const float wd1y = Wd1[l*3+1];
  const float wd1z = Wd1[l*3+2];
  const float bd1l = bd1[l];
  const float bd2l = bd2[l];
  const float bgl  = bg[l];

  float wd2[64]; load_row64(Wd2 + l * D, wd2);
  float wg [64]; load_row64(Wg  + l * D, wg);

  const size_t po = (size_t)wid * D;
  const float phil = phi[po + l];
  const int* ki = knn_idx + (size_t)wid * KNN;

  float acc = 0.f;
  #pragma unroll 1
  for (int kk = 0; kk < KNN; ++kk) {
    int j = ki[kk];
    float dx = xi - xb[j*3+0];
    float dy = yi - xb[j*3+1];
    float dz = zi - xb[j*3+2];

    // delta = relu((diff @ Wd1^T + bd1) @ Wd2^T + bd2)
    float t = fmaf(wd1z, dz, fmaf(wd1y, dy, fmaf(wd1x, dx, bd1l)));
    float h = bd2l + matvec64(wd2, t);
    float delta = fmaxf(h, 0.f);

    size_t jo = ((size_t)(b * NP + j)) * D + l;
    float psij = psi[jo];
    float alj  = al [jo];

    float beta = phil - psij + delta;
    float gam  = bgl + matvec64(wg, beta);

    // softmax over the 64 channels (lanes)
    float m = gam;
    #pragma unroll
    for (int s = 32; s >= 1; s >>= 1) m = fmaxf(m, __shfl_xor(m, s, 64));
    float e = __expf(gam - m);
    float ssum = e;
    #pragma unroll
    for (int s = 32; s >= 1; s >>= 1) ssum += __shfl_xor(ssum, s, 64);
    float rho = e / ssum;

    acc = fmaf(rho, alj + delta, acc);
  }

  // out = acc @ W2^T + b2 + feat  (residual), store f32
  float w2r[64]; load_row64(W2 + l * D, w2r);
  out[po + l] = b2[l] + matvec64(w2r, acc) + feat[po + l];
}

extern "C" void kernel_launch(void* const* d_in, const int* in_sizes, int n_in,
                              void* d_out, int out_size, void* d_ws, size_t ws_size,
                              hipStream_t stream) {
  const float* xyz  = (const float*)d_in[0];
  const float* feat = (const float*)d_in[1];
  // d_in[2] = k (int32) == 16, compile-time constant here
  const float* W1   = (const float*)d_in[3];
  const float* b1   = (const float*)d_in[4];
  const float* Wphi = (const float*)d_in[5];
  const float* bphi = (const float*)d_in[6];
  const float* Wpsi = (const float*)d_in[7];
  const float* bpsi = (const float*)d_in[8];
  const float* Wal  = (const float*)d_in[9];
  const float* bal  = (const float*)d_in[10];
  const float* Wg   = (const float*)d_in[11];
  const float* bg   = (const float*)d_in[12];
  const float* Wd1  = (const float*)d_in[13];
  const float* bd1  = (const float*)d_in[14];
  const float* Wd2  = (const float*)d_in[15];
  const float* bd2  = (const float*)d_in[16];
  const float* W2   = (const float*)d_in[17];
  const float* b2   = (const float*)d_in[18];

  float* out = (float*)d_out;

  // workspace layout (f32): phi | psi | al | knn_idx | pts4  (~14 MiB)
  float* phi = (float*)d_ws;
  float* psi = phi + (size_t)NB * NP * D;
  float* al  = psi + (size_t)NB * NP * D;
  int* knn_idx = (int*)(al + (size_t)NB * NP * D);
  float4* pts4 = (float4*)(knn_idx + (size_t)NB * NP * KNN);

  // output 0: points_xyz passthrough (f32)
  hipMemcpyAsync(d_out, d_in[0], (size_t)NB * NP * 3 * sizeof(float),
                 hipMemcpyDeviceToDevice, stream);

  k_prep<<<NB * NP / 256, 256, 0, stream>>>(xyz, pts4);
  k_transform<<<NB * NP * 64 / 256, 256, 0, stream>>>(feat, W1, b1, Wphi, bphi,
                                                      Wpsi, bpsi, Wal, bal, phi, psi, al);
  k_knn3<<<NB * NP / 4, 256, 0, stream>>>(pts4, knn_idx);
  k_main<<<NB * NP * 64 / 256, 256, 0, stream>>>(xyz, feat, knn_idx, phi, psi, al,
                                                 Wd1, bd1, Wd2, bd2, Wg, bg, W2, b2,
                                                 out + (size_t)NB * NP * 3);
}

// Round 5
// 475.889 us; speedup vs baseline: 6.3202x; 1.1388x over previous
//
#include <hip/hip_runtime.h>

#define NB 2
#define NP 8192
#define D 64
#define KNN 16

__device__ __forceinline__ float bcast(float v, int lane) {
  return __uint_as_float((unsigned int)__builtin_amdgcn_readlane((int)__float_as_uint(v), lane));
}

// load a 64-element f32 row into 64 registers (16x dwordx4)
__device__ __forceinline__ void load_row64(const float* __restrict__ p, float (&w)[64]) {
  const float4* q = reinterpret_cast<const float4*>(p);
  #pragma unroll
  for (int i = 0; i < 16; ++i) {
    float4 v = q[i];
    w[i*4+0] = v.x; w[i*4+1] = v.y; w[i*4+2] = v.z; w[i*4+3] = v.w;
  }
}

// y[l] = sum_c w[c] * x_broadcast_from_lane_c   (all 64 lanes active)
__device__ __forceinline__ float matvec64(const float (&w)[64], float x) {
  float a0 = 0.f, a1 = 0.f, a2 = 0.f, a3 = 0.f;
  #pragma unroll
  for (int c = 0; c < 64; c += 4) {
    a0 = fmaf(w[c+0], bcast(x, c+0), a0);
    a1 = fmaf(w[c+1], bcast(x, c+1), a1);
    a2 = fmaf(w[c+2], bcast(x, c+2), a2);
    a3 = fmaf(w[c+3], bcast(x, c+3), a3);
  }
  return (a0 + a1) + (a2 + a3);
}

// ---------------- per-point feature transforms: phi, psi, alpha ----------------
__global__ void __launch_bounds__(256)
k_transform(const float* __restrict__ feat,
            const float* __restrict__ W1,   const float* __restrict__ b1,
            const float* __restrict__ Wphi, const float* __restrict__ bphi,
            const float* __restrict__ Wpsi, const float* __restrict__ bpsi,
            const float* __restrict__ Wal,  const float* __restrict__ bal,
            float* __restrict__ phi, float* __restrict__ psi, float* __restrict__ al)
{
  const int wid = (blockIdx.x * 256 + threadIdx.x) >> 6;   // point index in [0, NB*NP)
  const int l   = threadIdx.x & 63;                        // channel
  const size_t po = (size_t)wid * D;

  float fin = feat[po + l];
  float w[64];

  load_row64(W1 + l * D, w);
  float f  = b1[l]   + matvec64(w, fin);
  load_row64(Wphi + l * D, w);
  float ph = bphi[l] + matvec64(w, f);
  load_row64(Wpsi + l * D, w);
  float ps = bpsi[l] + matvec64(w, f);
  load_row64(Wal + l * D, w);
  float av = bal[l]  + matvec64(w, f);

  phi[po + l] = ph;
  psi[po + l] = ps;
  al [po + l] = av;
}

// ---------------- prep: pack (x, y, z, |p|^2) per point ----------------
__global__ void __launch_bounds__(256)
k_prep(const float* __restrict__ xyz, float4* __restrict__ pts4)
{
  const int t = blockIdx.x * 256 + threadIdx.x;   // 0 .. NB*NP-1
  const float x = xyz[t*3+0];
  const float y = xyz[t*3+1];
  const float z = xyz[t*3+2];
  const float sq = __fadd_rn(__fadd_rn(__fmul_rn(x,x), __fmul_rn(y,y)), __fmul_rn(z,z));
  pts4[t] = make_float4(x, y, z, sq);
}

// ---------------- KNN v3: wave-distributed exact top-16, d2 prefilter ----------------
// Lanes 0..15 hold the running global top-16 as ascending u64 keys
// key = (bits(sqrt(d2)) << 16) | idx  (exact (distance, index) order).
__global__ void __launch_bounds__(256)
k_knn3(const float4* __restrict__ pts4, int* __restrict__ knn_idx)
{
  const int q    = (blockIdx.x * 256 + threadIdx.x) >> 6;  // global query id
  const int lane = threadIdx.x & 63;
  const int b    = q >> 13;
  const float4* pb = pts4 + (size_t)b * NP;

  const float4 qp = pb[q & (NP - 1)];          // uniform per wave -> scalar load
  const float xi = qp.x, yi = qp.y, zi = qp.z, sqi = qp.w;

  // ---- init: candidates 0..63, one per lane; full bitonic sort across lanes ----
  unsigned long long key;
  {
    float4 p = pb[lane];
    float dot = __fadd_rn(__fadd_rn(__fmul_rn(xi,p.x), __fmul_rn(yi,p.y)), __fmul_rn(zi,p.z));
    float d2  = __fsub_rn(__fadd_rn(sqi, p.w), __fmul_rn(2.0f, dot));
    float ds  = __fsqrt_rn(fmaxf(d2, 0.0f));
    key = (((unsigned long long)__float_as_uint(ds)) << 16) | (unsigned)lane;
  }
  #pragma unroll
  for (int k = 2; k <= 64; k <<= 1) {
    #pragma unroll
    for (int j = k >> 1; j >= 1; j >>= 1) {
      unsigned long long other = __shfl_xor(key, j, 64);
      const bool up    = (lane & k) == 0;        // ascending block (k=64: all)
      const bool lower = (lane & j) == 0;
      const bool takemin = (lower == up);
      const bool omin = other < key;
      key = (takemin == omin) ? other : key;
    }
  }
  // lanes 0..15: 16 smallest ascending; park +inf elsewhere
  if (lane >= KNN) key = ~0ull;

  float thr_d2;
  {
    float ds16 = __uint_as_float((unsigned int)(__shfl(key, KNN - 1, 64) >> 16));
    thr_d2 = __fmul_rn(__fmul_rn(ds16, ds16), 1.000001f);   // safe over-approx
  }

  // ---- main scan: batches of 64 candidates, 1-ahead prefetch ----
  float4 pcur = pb[64 + lane];
  #pragma unroll 1
  for (int c = 1; c < NP / 64; ++c) {
    float4 pnext;
    if (c + 1 < NP / 64) pnext = pb[(c + 1) * 64 + lane];
    else                 pnext = pcur;

    const int j = c * 64 + lane;
    float dot = __fadd_rn(__fadd_rn(__fmul_rn(xi,pcur.x), __fmul_rn(yi,pcur.y)), __fmul_rn(zi,pcur.z));
    float d2  = __fsub_rn(__fadd_rn(sqi, pcur.w), __fmul_rn(2.0f, dot));

    unsigned long long mask = __ballot(d2 <= thr_d2);
    if (mask) {
      float ds = __fsqrt_rn(fmaxf(d2, 0.0f));
      unsigned long long kc =
          (((unsigned long long)__float_as_uint(ds)) << 16) | (unsigned)j;
      do {
        const int src = __ffsll((long long)mask) - 1;
        mask &= mask - 1;
        const unsigned long long kin = __shfl(kc, src, 64);
        const int pos = __popcll(__ballot((lane < KNN) && (key < kin)));
        if (pos < KNN) {                          // else kin >= current 16th: skip
          unsigned long long up = __shfl_up(key, 1, 64);
          unsigned long long nk = (lane < pos) ? key : (lane == pos ? kin : up);
          if (lane < KNN) key = nk;
          float ds16 = __uint_as_float((unsigned int)(__shfl(key, KNN - 1, 64) >> 16));
          thr_d2 = __fmul_rn(__fmul_rn(ds16, ds16), 1.000001f);
        }
      } while (mask);
    }
    pcur = pnext;
  }

  if (lane < KNN) knn_idx[(size_t)q * KNN + lane] = (int)(key & 0xffffu);
}

// ---------------- main per-pair kernel: one wave per point ----------------
// __launch_bounds__(256, 2): allow ~256 VGPR so wd2[64]+wg[64] stay resident
// (at the default budget the compiler sank the weight loads into the K-loop:
//  VGPR_Count was 88 with 128 floats of declared persistent state).
__global__ void __launch_bounds__(256, 2)
k_main(const float* __restrict__ xyz,
       const float* __restrict__ feat,
       const int* __restrict__ knn_idx,
       const float* __restrict__ phi, const float* __restrict__ psi, const float* __restrict__ al,
       const float* __restrict__ Wd1, const float* __restrict__ bd1,
       const float* __restrict__ Wd2, const float* __restrict__ bd2,
       const float* __restrict__ Wg,  const float* __restrict__ bg,
       const float* __restrict__ W2,  const float* __restrict__ b2,
       float* __restrict__ out)
{
  const int wid = (blockIdx.x * 256 + threadIdx.x) >> 6;   // point index
  const int l   = threadIdx.x & 63;                        // channel
  const int b   = wid >> 13;
  const int i   = wid & (NP - 1);
  const float* xb = xyz + (size_t)b * NP * 3;

  const float xi = xb[i*3+0];
  const float yi = xb[i*3+1];
  const float zi = xb[i*3+2];

  const float wd1x = Wd1[l*3+0];
  const float wd1y = Wd1[l*3+1];
  const float wd1z = Wd1[l*3+2];
  const float bd1l = bd1[l];
  const float bd2l = bd2[l];
  const float bgl  = bg[l];

  float wd2[64]; load_row64(Wd2 + l * D, wd2);
  float wg [64]; load_row64(Wg  + l * D, wg);

  const size_t po = (size_t)wid * D;
  const float phil = phi[po + l];

  // all 16 neighbor indices in one coalesced load, lanes 0..15
  int kiv = 0;
  if (l < KNN) kiv = knn_idx[(size_t)wid * KNN + l];

  // software pipeline: prefetch iteration kk+1's gathers during iteration kk
  int j = __builtin_amdgcn_readlane(kiv, 0);
  size_t jo = ((size_t)(b * NP + j)) * D + l;
  float psij = psi[jo];
  float alj  = al [jo];
  float xjx = xb[j*3+0], xjy = xb[j*3+1], xjz = xb[j*3+2];

  float acc = 0.f;
  #pragma unroll 1
  for (int kk = 0; kk < KNN; ++kk) {
    const int kn = (kk < KNN-1) ? kk + 1 : kk;
    const int jn = __builtin_amdgcn_readlane(kiv, kn);
    const size_t jon = ((size_t)(b * NP + jn)) * D + l;
    float psin = psi[jon];
    float aln  = al [jon];
    float xnx = xb[jn*3+0], xny = xb[jn*3+1], xnz = xb[jn*3+2];

    float dx = xi - xjx;
    float dy = yi - xjy;
    float dz = zi - xjz;

    // delta = relu((diff @ Wd1^T + bd1) @ Wd2^T + bd2)
    float t = fmaf(wd1z, dz, fmaf(wd1y, dy, fmaf(wd1x, dx, bd1l)));
    float h = bd2l + matvec64(wd2, t);
    float delta = fmaxf(h, 0.f);

    float beta = phil - psij + delta;
    float gam  = bgl + matvec64(wg, beta);

    // softmax over the 64 channels (lanes)
    float m = gam;
    #pragma unroll
    for (int s = 32; s >= 1; s >>= 1) m = fmaxf(m, __shfl_xor(m, s, 64));
    float e = __expf(gam - m);
    float ssum = e;
    #pragma unroll
    for (int s = 32; s >= 1; s >>= 1) ssum += __shfl_xor(ssum, s, 64);
    float rho = e / ssum;

    acc = fmaf(rho, alj + delta, acc);

    psij = psin; alj = aln; xjx = xnx; xjy = xny; xjz = xnz;
  }

  // out = acc @ W2^T + b2 + feat  (residual), store f32
  float w2r[64]; load_row64(W2 + l * D, w2r);
  out[po + l] = b2[l] + matvec64(w2r, acc) + feat[po + l];
}

extern "C" void kernel_launch(void* const* d_in, const int* in_sizes, int n_in,
                              void* d_out, int out_size, void* d_ws, size_t ws_size,
                              hipStream_t stream) {
  const float* xyz  = (const float*)d_in[0];
  const float* feat = (const float*)d_in[1];
  // d_in[2] = k (int32) == 16, compile-time constant here
  const float* W1   = (const float*)d_in[3];
  const float* b1   = (const float*)d_in[4];
  const float* Wphi = (const float*)d_in[5];
  const float* bphi = (const float*)d_in[6];
  const float* Wpsi = (const float*)d_in[7];
  const float* bpsi = (const float*)d_in[8];
  const float* Wal  = (const float*)d_in[9];
  const float* bal  = (const float*)d_in[10];
  const float* Wg   = (const float*)d_in[11];
  const float* bg   = (const float*)d_in[12];
  const float* Wd1  = (const float*)d_in[13];
  const float* bd1  = (const float*)d_in[14];
  const float* Wd2  = (const float*)d_in[15];
  const float* bd2  = (const float*)d_in[16];
  const float* W2   = (const float*)d_in[17];
  const float* b2   = (const float*)d_in[18];

  float* out = (float*)d_out;

  // workspace layout (f32): phi | psi | al | knn_idx | pts4  (~14 MiB)
  float* phi = (float*)d_ws;
  float* psi = phi + (size_t)NB * NP * D;
  float* al  = psi + (size_t)NB * NP * D;
  int* knn_idx = (int*)(al + (size_t)NB * NP * D);
  float4* pts4 = (float4*)(knn_idx + (size_t)NB * NP * KNN);

  // output 0: points_xyz passthrough (f32)
  hipMemcpyAsync(d_out, d_in[0], (size_t)NB * NP * 3 * sizeof(float),
                 hipMemcpyDeviceToDevice, stream);

  k_prep<<<NB * NP / 256, 256, 0, stream>>>(xyz, pts4);
  k_transform<<<NB * NP * 64 / 256, 256, 0, stream>>>(feat, W1, b1, Wphi, bphi,
                                                      Wpsi, bpsi, Wal, bal, phi, psi, al);
  k_knn3<<<NB * NP / 4, 256, 0, stream>>>(pts4, knn_idx);
  k_main<<<NB * NP * 64 / 256, 256, 0, stream>>>(xyz, feat, knn_idx, phi, psi, al,
                                                 Wd1, bd1, Wd2, bd2, Wg, bg, W2, b2,
                                                 out + (size_t)NB * NP * 3);
}

// Round 6
// 365.902 us; speedup vs baseline: 8.2200x; 1.3006x over previous
//
#include <hip/hip_runtime.h>

#define NB 2
#define NP 8192
#define D 64
#define KNN 16

__device__ __forceinline__ float bcast(float v, int lane) {
  return __uint_as_float((unsigned int)__builtin_amdgcn_readlane((int)__float_as_uint(v), lane));
}

// load a 64-element f32 row into 64 registers (16x dwordx4)
__device__ __forceinline__ void load_row64(const float* __restrict__ p, float (&w)[64]) {
  const float4* q = reinterpret_cast<const float4*>(p);
  #pragma unroll
  for (int i = 0; i < 16; ++i) {
    float4 v = q[i];
    w[i*4+0] = v.x; w[i*4+1] = v.y; w[i*4+2] = v.z; w[i*4+3] = v.w;
  }
}

// y[l] = sum_c w[c] * x_broadcast_from_lane_c   (all 64 lanes active)
__device__ __forceinline__ float matvec64(const float (&w)[64], float x) {
  float a0 = 0.f, a1 = 0.f, a2 = 0.f, a3 = 0.f;
  #pragma unroll
  for (int c = 0; c < 64; c += 4) {
    a0 = fmaf(w[c+0], bcast(x, c+0), a0);
    a1 = fmaf(w[c+1], bcast(x, c+1), a1);
    a2 = fmaf(w[c+2], bcast(x, c+2), a2);
    a3 = fmaf(w[c+3], bcast(x, c+3), a3);
  }
  return (a0 + a1) + (a2 + a3);
}

// ---------------- per-point feature transforms: phi, psi, alpha ----------------
__global__ void __launch_bounds__(256)
k_transform(const float* __restrict__ feat,
            const float* __restrict__ W1,   const float* __restrict__ b1,
            const float* __restrict__ Wphi, const float* __restrict__ bphi,
            const float* __restrict__ Wpsi, const float* __restrict__ bpsi,
            const float* __restrict__ Wal,  const float* __restrict__ bal,
            float* __restrict__ phi, float* __restrict__ psi, float* __restrict__ al)
{
  const int wid = (blockIdx.x * 256 + threadIdx.x) >> 6;   // point index in [0, NB*NP)
  const int l   = threadIdx.x & 63;                        // channel
  const size_t po = (size_t)wid * D;

  float fin = feat[po + l];
  float w[64];

  load_row64(W1 + l * D, w);
  float f  = b1[l]   + matvec64(w, fin);
  load_row64(Wphi + l * D, w);
  float ph = bphi[l] + matvec64(w, f);
  load_row64(Wpsi + l * D, w);
  float ps = bpsi[l] + matvec64(w, f);
  load_row64(Wal + l * D, w);
  float av = bal[l]  + matvec64(w, f);

  phi[po + l] = ph;
  psi[po + l] = ps;
  al [po + l] = av;
}

// ---------------- prep: pack (x, y, z, |p|^2) per point ----------------
__global__ void __launch_bounds__(256)
k_prep(const float* __restrict__ xyz, float4* __restrict__ pts4)
{
  const int t = blockIdx.x * 256 + threadIdx.x;   // 0 .. NB*NP-1
  const float x = xyz[t*3+0];
  const float y = xyz[t*3+1];
  const float z = xyz[t*3+2];
  const float sq = __fadd_rn(__fadd_rn(__fmul_rn(x,x), __fmul_rn(y,y)), __fmul_rn(z,z));
  pts4[t] = make_float4(x, y, z, sq);
}

// ---------------- fold the linear delta-MLP: Weff = Wd2@Wd1, beff = Wd2@bd1+bd2 ----
__global__ void k_fold(const float* __restrict__ Wd1, const float* __restrict__ bd1,
                       const float* __restrict__ Wd2, const float* __restrict__ bd2,
                       float4* __restrict__ weff)
{
  const int c = threadIdx.x;   // 64 threads, 1 block
  float wx = 0.f, wy = 0.f, wz = 0.f, be = bd2[c];
  for (int k = 0; k < 64; ++k) {
    float w = Wd2[c*64 + k];
    wx = fmaf(w, Wd1[k*3+0], wx);
    wy = fmaf(w, Wd1[k*3+1], wy);
    wz = fmaf(w, Wd1[k*3+2], wz);
    be = fmaf(w, bd1[k], be);
  }
  weff[c] = make_float4(wx, wy, wz, be);
}

// ---------------- KNN v4: depth-4 prefetch, PARK init, exact top-16 ----------------
__global__ void __launch_bounds__(256)
k_knn4(const float4* __restrict__ pts4, int* __restrict__ knn_idx)
{
  const int q    = (blockIdx.x * 256 + threadIdx.x) >> 6;  // global query id
  const int lane = threadIdx.x & 63;
  const int b    = q >> 13;
  const float4* pb = pts4 + (size_t)b * NP;

  const float4 qp = pb[q & (NP - 1)];          // uniform per wave -> scalar load
  const float xi = qp.x, yi = qp.y, zi = qp.z, sqi = qp.w;

  // parked key: FLT_MAX distance bits, idx 0xffff -> larger than any real key
  const unsigned long long PARK = (0x7F7FFFFFull << 16) | 0xFFFFull;
  unsigned long long key = PARK;               // lanes 0..15: running global top-16
  float thr_d2 = __builtin_inff();

#define KNN_PROC(P, CIDX)                                                               \
  {                                                                                     \
    float dot = __fadd_rn(__fadd_rn(__fmul_rn(xi,(P).x), __fmul_rn(yi,(P).y)),          \
                          __fmul_rn(zi,(P).z));                                         \
    float d2  = __fsub_rn(__fadd_rn(sqi, (P).w), __fmul_rn(2.0f, dot));                 \
    unsigned long long mask = __ballot(d2 <= thr_d2);                                   \
    if (mask) {                                                                         \
      float ds = __fsqrt_rn(fmaxf(d2, 0.0f));                                           \
      unsigned long long kc =                                                           \
          (((unsigned long long)__float_as_uint(ds)) << 16) |                           \
          (unsigned)((CIDX)*64 + lane);                                                 \
      do {                                                                              \
        const int src = __ffsll((long long)mask) - 1;                                   \
        mask &= mask - 1;                                                               \
        const unsigned long long kin = __shfl(kc, src, 64);                             \
        const int pos = __popcll(__ballot((lane < KNN) && (key < kin)));                \
        if (pos < KNN) {                                                                \
          unsigned long long up = __shfl_up(key, 1, 64);                                \
          unsigned long long nk = (lane < pos) ? key : (lane == pos ? kin : up);        \
          if (lane < KNN) key = nk;                                                     \
          float ds16 = __uint_as_float((unsigned int)(__shfl(key, KNN - 1, 64) >> 16)); \
          thr_d2 = __fmul_rn(__fmul_rn(ds16, ds16), 1.000001f);                         \
        }                                                                               \
      } while (mask);                                                                   \
    }                                                                                   \
  }

  float4 a0 = pb[lane], a1 = pb[64 + lane], a2 = pb[128 + lane], a3 = pb[192 + lane];
  #pragma unroll 1
  for (int g = 0; g < NP/256; ++g) {
    float4 n0, n1, n2, n3;
    if (g + 1 < NP/256) {
      const int base = (g + 1) * 256 + lane;
      n0 = pb[base]; n1 = pb[base + 64]; n2 = pb[base + 128]; n3 = pb[base + 192];
    } else {
      n0 = a0; n1 = a1; n2 = a2; n3 = a3;
    }
    KNN_PROC(a0, g*4+0)
    KNN_PROC(a1, g*4+1)
    KNN_PROC(a2, g*4+2)
    KNN_PROC(a3, g*4+3)
    a0 = n0; a1 = n1; a2 = n2; a3 = n3;
  }
#undef KNN_PROC

  if (lane < KNN) knn_idx[(size_t)q * KNN + lane] = (int)(key & 0xffffu);
}

// ---------------- main kernel v2: lane = pair, LDS weights, register GEMM ----------
// Block = 256 threads = 4 waves = 16 points (4 points/wave, 16 kslots each).
__global__ void __launch_bounds__(256, 2)
k_main2(const float* __restrict__ xyz,
        const float* __restrict__ feat,
        const int* __restrict__ knn_idx,
        const float* __restrict__ phi, const float* __restrict__ psi, const float* __restrict__ al,
        const float4* __restrict__ weff,
        const float* __restrict__ Wg,  const float* __restrict__ bg,
        const float* __restrict__ W2g, const float* __restrict__ b2g,
        float* __restrict__ out)
{
  __shared__ float4 sWg4[64 * 16];    // Wg row-major [o][c], float4 chunks, 16KB
  __shared__ float  sW2[64 * 65];     // W2 +1-padded rows (bank-conflict-free), 16.25KB
  __shared__ float4 sWeff[64];        // (wx, wy, wz, beff) per channel, 1KB
  __shared__ float4 sBg4[16];         // bg, 256B
  __shared__ float  sB2[64];          // 256B

  const int tid = threadIdx.x;

  // ---- stage weights into LDS (once per block) ----
  {
    const float4* wg4 = (const float4*)Wg;
    #pragma unroll
    for (int it = 0; it < 4; ++it) sWg4[it*256 + tid] = wg4[it*256 + tid];
    #pragma unroll
    for (int it = 0; it < 16; ++it) {
      int e = it*256 + tid;           // 0..4095
      sW2[(e >> 6)*65 + (e & 63)] = W2g[e];
    }
    if (tid < 64) { sB2[tid] = b2g[tid]; sWeff[tid] = weff[tid]; }
    if (tid < 16) sBg4[tid] = ((const float4*)bg)[tid];
  }
  __syncthreads();

  const int lane  = tid & 63;
  const int kslot = lane & 15;
  const int point = blockIdx.x * 16 + (tid >> 6) * 4 + (lane >> 4);
  const int b     = point >> 13;
  const int i     = point & (NP - 1);
  const size_t irow = (size_t)point * D;

  const int j = knn_idx[(size_t)blockIdx.x * 256 + tid];   // coalesced: point*16+kslot
  const size_t jrow = ((size_t)(b * NP + j)) * D;

  const float* xb = xyz + (size_t)b * NP * 3;
  const float dx = xb[i*3+0] - xb[j*3+0];
  const float dy = xb[i*3+1] - xb[j*3+1];
  const float dz = xb[i*3+2] - xb[j*3+2];

  // ---- prologue: beta = phi_i - psi_j + delta ; alpha = al_j + delta ----
  float beta[64], alpha[64];
  #pragma unroll
  for (int cc = 0; cc < 16; ++cc) {
    float4 ph = *(const float4*)(phi + irow + cc*4);
    float4 ps = *(const float4*)(psi + jrow + cc*4);
    float4 av = *(const float4*)(al  + jrow + cc*4);
    float phv[4] = {ph.x, ph.y, ph.z, ph.w};
    float psv[4] = {ps.x, ps.y, ps.z, ps.w};
    float avv[4] = {av.x, av.y, av.z, av.w};
    #pragma unroll
    for (int r = 0; r < 4; ++r) {
      const int c = cc*4 + r;
      float4 wf = sWeff[c];           // wave-uniform -> broadcast, conflict-free
      float t = fmaf(wf.z, dz, fmaf(wf.y, dy, fmaf(wf.x, dx, wf.w)));
      float d = fmaxf(t, 0.f);
      beta[c]  = phv[r] - psv[r] + d;
      alpha[c] = avv[r] + d;
    }
  }

  // ---- GEMM: gamma = beta @ Wg^T + bg  (weights from LDS, uniform broadcast) ----
  float gamma[64];
  #pragma unroll
  for (int og = 0; og < 16; ++og) {   // 4 output channels at a time (4 indep chains)
    float4 bgv = sBg4[og];
    float g0 = bgv.x, g1 = bgv.y, g2 = bgv.z, g3 = bgv.w;
    #pragma unroll
    for (int c4 = 0; c4 < 16; ++c4) {
      float4 w0 = sWg4[(og*4+0)*16 + c4];
      float4 w1 = sWg4[(og*4+1)*16 + c4];
      float4 w2 = sWg4[(og*4+2)*16 + c4];
      float4 w3 = sWg4[(og*4+3)*16 + c4];
      g0 = fmaf(w0.x, beta[c4*4+0], g0); g0 = fmaf(w0.y, beta[c4*4+1], g0);
      g0 = fmaf(w0.z, beta[c4*4+2], g0); g0 = fmaf(w0.w, beta[c4*4+3], g0);
      g1 = fmaf(w1.x, beta[c4*4+0], g1); g1 = fmaf(w1.y, beta[c4*4+1], g1);
      g1 = fmaf(w1.z, beta[c4*4+2], g1); g1 = fmaf(w1.w, beta[c4*4+3], g1);
      g2 = fmaf(w2.x, beta[c4*4+0], g2); g2 = fmaf(w2.y, beta[c4*4+1], g2);
      g2 = fmaf(w2.z, beta[c4*4+2], g2); g2 = fmaf(w2.w, beta[c4*4+3], g2);
      g3 = fmaf(w3.x, beta[c4*4+0], g3); g3 = fmaf(w3.y, beta[c4*4+1], g3);
      g3 = fmaf(w3.z, beta[c4*4+2], g3); g3 = fmaf(w3.w, beta[c4*4+3], g3);
    }
    gamma[og*4+0] = g0; gamma[og*4+1] = g1; gamma[og*4+2] = g2; gamma[og*4+3] = g3;
  }

  // ---- lane-local softmax over 64 channels ----
  float m0 = gamma[0], m1 = gamma[1], m2 = gamma[2], m3 = gamma[3];
  #pragma unroll
  for (int c = 4; c < 64; c += 4) {
    m0 = fmaxf(m0, gamma[c+0]); m1 = fmaxf(m1, gamma[c+1]);
    m2 = fmaxf(m2, gamma[c+2]); m3 = fmaxf(m3, gamma[c+3]);
  }
  const float m = fmaxf(fmaxf(m0, m1), fmaxf(m2, m3));
  float s0 = 0.f, s1 = 0.f, s2 = 0.f, s3 = 0.f;
  #pragma unroll
  for (int c = 0; c < 64; c += 4) {
    gamma[c+0] = __expf(gamma[c+0] - m); s0 += gamma[c+0];
    gamma[c+1] = __expf(gamma[c+1] - m); s1 += gamma[c+1];
    gamma[c+2] = __expf(gamma[c+2] - m); s2 += gamma[c+2];
    gamma[c+3] = __expf(gamma[c+3] - m); s3 += gamma[c+3];
  }
  const float inv = 1.0f / ((s0 + s1) + (s2 + s3));

  // ---- weighted sum over K: reduce rho*alpha across the 16 kslot lanes ----
  #pragma unroll
  for (int c = 0; c < 64; ++c) {
    float v = gamma[c] * inv * alpha[c];
    v += __shfl_xor(v, 1, 64);
    v += __shfl_xor(v, 2, 64);
    v += __shfl_xor(v, 4, 64);
    v += __shfl_xor(v, 8, 64);
    alpha[c] = v;                      // per-point acc, replicated in 16 lanes
  }

  // ---- epilogue: out = acc @ W2^T + b2 + feat; lane kslot does channels 4k..4k+3 ----
  const int oc = kslot * 4;
  float o0 = sB2[oc+0], o1 = sB2[oc+1], o2 = sB2[oc+2], o3 = sB2[oc+3];
  #pragma unroll
  for (int c = 0; c < 64; ++c) {
    o0 = fmaf(sW2[(oc+0)*65 + c], alpha[c], o0);
    o1 = fmaf(sW2[(oc+1)*65 + c], alpha[c], o1);
    o2 = fmaf(sW2[(oc+2)*65 + c], alpha[c], o2);
    o3 = fmaf(sW2[(oc+3)*65 + c], alpha[c], o3);
  }
  float4 fv = *(const float4*)(feat + irow + oc);
  *(float4*)(out + irow + oc) = make_float4(o0 + fv.x, o1 + fv.y, o2 + fv.z, o3 + fv.w);
}

extern "C" void kernel_launch(void* const* d_in, const int* in_sizes, int n_in,
                              void* d_out, int out_size, void* d_ws, size_t ws_size,
                              hipStream_t stream) {
  const float* xyz  = (const float*)d_in[0];
  const float* feat = (const float*)d_in[1];
  // d_in[2] = k (int32) == 16, compile-time constant here
  const float* W1   = (const float*)d_in[3];
  const float* b1   = (const float*)d_in[4];
  const float* Wphi = (const float*)d_in[5];
  const float* bphi = (const float*)d_in[6];
  const float* Wpsi = (const float*)d_in[7];
  const float* bpsi = (const float*)d_in[8];
  const float* Wal  = (const float*)d_in[9];
  const float* bal  = (const float*)d_in[10];
  const float* Wg   = (const float*)d_in[11];
  const float* bg   = (const float*)d_in[12];
  const float* Wd1  = (const float*)d_in[13];
  const float* bd1  = (const float*)d_in[14];
  const float* Wd2  = (const float*)d_in[15];
  const float* bd2  = (const float*)d_in[16];
  const float* W2   = (const float*)d_in[17];
  const float* b2   = (const float*)d_in[18];

  float* out = (float*)d_out;

  // workspace layout (f32): phi | psi | al | knn_idx | pts4 | weff  (~13.5 MiB)
  float* phi = (float*)d_ws;
  float* psi = phi + (size_t)NB * NP * D;
  float* al  = psi + (size_t)NB * NP * D;
  int* knn_idx = (int*)(al + (size_t)NB * NP * D);
  float4* pts4 = (float4*)(knn_idx + (size_t)NB * NP * KNN);
  float4* weff = pts4 + (size_t)NB * NP;

  // output 0: points_xyz passthrough (f32)
  hipMemcpyAsync(d_out, d_in[0], (size_t)NB * NP * 3 * sizeof(float),
                 hipMemcpyDeviceToDevice, stream);

  k_prep<<<NB * NP / 256, 256, 0, stream>>>(xyz, pts4);
  k_fold<<<1, 64, 0, stream>>>(Wd1, bd1, Wd2, bd2, weff);
  k_transform<<<NB * NP * 64 / 256, 256, 0, stream>>>(feat, W1, b1, Wphi, bphi,
                                                      Wpsi, bpsi, Wal, bal, phi, psi, al);
  k_knn4<<<NB * NP / 4, 256, 0, stream>>>(pts4, knn_idx);
  k_main2<<<NB * NP / 16, 256, 0, stream>>>(xyz, feat, knn_idx, phi, psi, al,
                                            weff, Wg, bg, W2, b2,
                                            out + (size_t)NB * NP * 3);
}

// Round 7
// 241.055 us; speedup vs baseline: 12.4772x; 1.5179x over previous
//
#include <hip/hip_runtime.h>

#define NB 2
#define NP 8192
#define D 64
#define KNN 16

// ---------------- prep: pack (x, y, z, |p|^2) per point ----------------
__global__ void __launch_bounds__(256)
k_prep(const float* __restrict__ xyz, float4* __restrict__ pts4)
{
  const int t = blockIdx.x * 256 + threadIdx.x;   // 0 .. NB*NP-1
  const float x = xyz[t*3+0];
  const float y = xyz[t*3+1];
  const float z = xyz[t*3+2];
  const float sq = __fadd_rn(__fadd_rn(__fmul_rn(x,x), __fmul_rn(y,y)), __fmul_rn(z,z));
  pts4[t] = make_float4(x, y, z, sq);
}

// ---------------- fold delta-MLP: Weff = Wd2@Wd1, beff = Wd2@bd1+bd2 ----------
__global__ void k_fold(const float* __restrict__ Wd1, const float* __restrict__ bd1,
                       const float* __restrict__ Wd2, const float* __restrict__ bd2,
                       float4* __restrict__ weff)
{
  const int c = threadIdx.x;   // 64 threads, 1 block
  float wx = 0.f, wy = 0.f, wz = 0.f, be = bd2[c];
  for (int k = 0; k < 64; ++k) {
    float w = Wd2[c*64 + k];
    wx = fmaf(w, Wd1[k*3+0], wx);
    wy = fmaf(w, Wd1[k*3+1], wy);
    wz = fmaf(w, Wd1[k*3+2], wz);
    be = fmaf(w, bd1[k], be);
  }
  weff[c] = make_float4(wx, wy, wz, be);
}

// ---------------- fold the point-side GEMMs --------------------------------
// block 0: Af = Wg@Wphi@W1, dA = Wg@(Wphi b1 + bphi) + bg
// block 1: Bf = Wg@Wpsi@W1, dB = Wg@(Wpsi b1 + bpsi)
// block 2: Cf = Wal@W1,     dC = Wal b1 + bal
__global__ void __launch_bounds__(256)
k_fold2(const float* __restrict__ Wg,   const float* __restrict__ bg,
        const float* __restrict__ Wphi, const float* __restrict__ bphi,
        const float* __restrict__ Wpsi, const float* __restrict__ bpsi,
        const float* __restrict__ Wal,  const float* __restrict__ bal,
        const float* __restrict__ W1,   const float* __restrict__ b1,
        float* __restrict__ Af, float* __restrict__ dAv,
        float* __restrict__ Bf, float* __restrict__ dBv,
        float* __restrict__ Cf, float* __restrict__ dCv)
{
  __shared__ float sT[64 * 65];   // intermediate T (pad 65, b32 access)
  __shared__ float sTb[64];
  const int m = blockIdx.x;
  const int o = threadIdx.x >> 2;     // out row
  const int q = threadIdx.x & 3;      // 16-col quarter

  const float* O  = (m == 2) ? Wal : Wg;
  const float* M  = (m == 0) ? Wphi : Wpsi;
  const float* bM = (m == 0) ? bphi : bpsi;

  if (m == 2) {
    for (int cc = 0; cc < 16; ++cc) sT[o*65 + q*16 + cc] = Wal[o*64 + q*16 + cc];
    if (q == 0) sTb[o] = bal[o];
  } else {
    float acc[16];
    #pragma unroll
    for (int cc = 0; cc < 16; ++cc) acc[cc] = 0.f;
    for (int k = 0; k < 64; ++k) {
      float w = O[o*64 + k];
      #pragma unroll
      for (int cc = 0; cc < 16; ++cc) acc[cc] = fmaf(w, M[k*64 + q*16 + cc], acc[cc]);
    }
    for (int cc = 0; cc < 16; ++cc) sT[o*65 + q*16 + cc] = acc[cc];
    if (q == 0) {
      float tb = (m == 0) ? bg[o] : 0.f;
      for (int k = 0; k < 64; ++k) tb = fmaf(O[o*64 + k], bM[k], tb);
      sTb[o] = tb;
    }
  }
  __syncthreads();

  // stage 2: R = T @ W1, dR = T @ b1 + Tb
  float acc[16];
  #pragma unroll
  for (int cc = 0; cc < 16; ++cc) acc[cc] = 0.f;
  for (int k = 0; k < 64; ++k) {
    float w = sT[o*65 + k];
    #pragma unroll
    for (int cc = 0; cc < 16; ++cc) acc[cc] = fmaf(w, W1[k*64 + q*16 + cc], acc[cc]);
  }
  float* R  = (m == 0) ? Af  : (m == 1) ? Bf  : Cf;
  float* dR = (m == 0) ? dAv : (m == 1) ? dBv : dCv;
  for (int cc = 0; cc < 16; ++cc) R[o*64 + q*16 + cc] = acc[cc];
  if (q == 0) {
    float db = sTb[o];
    for (int k = 0; k < 64; ++k) db = fmaf(sT[o*65 + k], b1[k], db);
    dR[o] = db;
  }
}

// ---------------- per-point GEMVs: uA = Af x + dA, uB = Bf x + dB, uC = Cf x + dC
__global__ void __launch_bounds__(256, 4)
k_transform2(const float* __restrict__ feat,
             const float* __restrict__ Af, const float* __restrict__ dAv,
             const float* __restrict__ Bf, const float* __restrict__ dBv,
             const float* __restrict__ Cf, const float* __restrict__ dCv,
             float* __restrict__ uA, float* __restrict__ uB, float* __restrict__ uC)
{
  __shared__ float sA[64*68], sB[64*68], sC[64*68];  // pad 68: b128-aligned, bank-spread
  __shared__ float sdA[64], sdB[64], sdC[64];

  const int tid = threadIdx.x;
  for (int e = tid; e < 4096; e += 256) {
    const int r = e >> 6, c = e & 63;
    sA[r*68 + c] = Af[e];
    sB[r*68 + c] = Bf[e];
    sC[r*68 + c] = Cf[e];
  }
  if (tid < 64) { sdA[tid] = dAv[tid]; sdB[tid] = dBv[tid]; sdC[tid] = dCv[tid]; }
  __syncthreads();

  const int q  = tid & 7;                       // out-eighth; rows o = q + 8i
  const int pt = blockIdx.x * 32 + (tid >> 3);
  const size_t row = (size_t)pt * D;

  float x[64];
  {
    const float4* xr = (const float4*)(feat + row);
    #pragma unroll
    for (int cc = 0; cc < 16; ++cc) {
      float4 v = xr[cc];
      x[cc*4+0] = v.x; x[cc*4+1] = v.y; x[cc*4+2] = v.z; x[cc*4+3] = v.w;
    }
  }

#define GEMV8(SM, SD, OUT)                                              \
  {                                                                     \
    float acc[8];                                                       \
    _Pragma("unroll")                                                   \
    for (int i = 0; i < 8; ++i) acc[i] = SD[q + 8*i];                   \
    _Pragma("unroll")                                                   \
    for (int i = 0; i < 8; ++i) {                                       \
      const int o = q + 8*i;                                            \
      const float4* wr = (const float4*)(SM + o*68);                    \
      _Pragma("unroll")                                                 \
      for (int c4 = 0; c4 < 16; ++c4) {                                 \
        float4 w = wr[c4];                                              \
        acc[i] = fmaf(w.x, x[c4*4+0], acc[i]);                          \
        acc[i] = fmaf(w.y, x[c4*4+1], acc[i]);                          \
        acc[i] = fmaf(w.z, x[c4*4+2], acc[i]);                          \
        acc[i] = fmaf(w.w, x[c4*4+3], acc[i]);                          \
      }                                                                 \
    }                                                                   \
    _Pragma("unroll")                                                   \
    for (int i = 0; i < 8; ++i) OUT[row + q + 8*i] = acc[i];            \
  }

  GEMV8(sA, sdA, uA)
  GEMV8(sB, sdB, uB)
  GEMV8(sC, sdC, uC)
#undef GEMV8
}

// ---------------- KNN v5: bitonic init, (ds,idx) split keys, lazy threshold ----
__global__ void __launch_bounds__(256)
k_knn5(const float4* __restrict__ pts4, int* __restrict__ knn_idx)
{
  const int q    = (blockIdx.x * 256 + threadIdx.x) >> 6;  // global query id
  const int lane = threadIdx.x & 63;
  const int b    = q >> 13;
  const float4* pb = pts4 + (size_t)b * NP;

  const float4 qp = pb[q & (NP - 1)];          // uniform per wave
  const float xi = qp.x, yi = qp.y, zi = qp.z, sqi = qp.w;

  float4 a0 = pb[lane], a1 = pb[64 + lane], a2 = pb[128 + lane], a3 = pb[192 + lane];

  // ---- init: batch 0 via full-wave bitonic sort of (ds, idx) ----
  unsigned kds, kidx;
  {
    float dot = __fadd_rn(__fadd_rn(__fmul_rn(xi,a0.x), __fmul_rn(yi,a0.y)), __fmul_rn(zi,a0.z));
    float d2  = __fsub_rn(__fadd_rn(sqi, a0.w), __fmul_rn(2.0f, dot));
    float ds  = __fsqrt_rn(fmaxf(d2, 0.0f));
    kds = __float_as_uint(ds);
    kidx = (unsigned)lane;
  }
  #pragma unroll
  for (int k = 2; k <= 64; k <<= 1) {
    #pragma unroll
    for (int jj = k >> 1; jj >= 1; jj >>= 1) {
      unsigned ods  = __shfl_xor(kds,  jj, 64);
      unsigned oidx = __shfl_xor(kidx, jj, 64);
      const bool up    = (lane & k) == 0;
      const bool lower = (lane & jj) == 0;
      const bool takemin = (lower == up);
      const bool oless = (ods < kds) || ((ods == kds) && (oidx < kidx));
      const bool take = (takemin == oless);
      kds  = take ? ods  : kds;
      kidx = take ? oidx : kidx;
    }
  }
  if (lane >= KNN) { kds = 0x7F7FFFFFu; kidx = 0xFFFFu; }

  float thr_d2;
  {
    float d16 = __uint_as_float((unsigned)__builtin_amdgcn_readlane((int)kds, KNN - 1));
    thr_d2 = __fmul_rn(__fmul_rn(d16, d16), 1.000001f);
  }

#define KPROC(P, CIDX)                                                                   \
  {                                                                                      \
    float dot = __fadd_rn(__fadd_rn(__fmul_rn(xi,(P).x), __fmul_rn(yi,(P).y)),           \
                          __fmul_rn(zi,(P).z));                                          \
    float d2  = __fsub_rn(__fadd_rn(sqi, (P).w), __fmul_rn(2.0f, dot));                  \
    unsigned long long mask = __ballot(d2 <= thr_d2);                                    \
    if (mask) {                                                                          \
      float ds = __fsqrt_rn(fmaxf(d2, 0.0f));                                            \
      unsigned cds = __float_as_uint(ds);                                                \
      unsigned cidx = (unsigned)((CIDX)*64 + lane);                                      \
      bool ins = false;                                                                  \
      do {                                                                               \
        const int src = __ffsll((long long)mask) - 1;                                    \
        mask &= mask - 1;                                                                \
        const unsigned ids  = (unsigned)__builtin_amdgcn_readlane((int)cds,  src);       \
        const unsigned iidx = (unsigned)__builtin_amdgcn_readlane((int)cidx, src);       \
        const bool less = (kds < ids) || ((kds == ids) && (kidx < iidx));                \
        const int pos = __popcll(__ballot((lane < KNN) && less));                        \
        if (pos < KNN) {                                                                 \
          unsigned uds  = __shfl_up(kds,  1, 64);                                        \
          unsigned uidx = __shfl_up(kidx, 1, 64);                                        \
          if (lane < KNN) {                                                              \
            kds  = (lane < pos) ? kds  : (lane == pos ? ids  : uds);                     \
            kidx = (lane < pos) ? kidx : (lane == pos ? iidx : uidx);                    \
          }                                                                              \
          ins = true;                                                                    \
        }                                                                                \
      } while (mask);                                                                    \
      if (ins) {                                                                         \
        float d16 = __uint_as_float((unsigned)__builtin_amdgcn_readlane((int)kds, KNN-1)); \
        thr_d2 = __fmul_rn(__fmul_rn(d16, d16), 1.000001f);                              \
      }                                                                                  \
    }                                                                                    \
  }

  // prefetch batches 4..7, process 1..3
  float4 n0 = pb[256 + lane], n1 = pb[320 + lane], n2 = pb[384 + lane], n3 = pb[448 + lane];
  KPROC(a1, 1) KPROC(a2, 2) KPROC(a3, 3)
  a0 = n0; a1 = n1; a2 = n2; a3 = n3;

  #pragma unroll 1
  for (int g = 1; g < 32; ++g) {
    if (g < 31) {
      const int base = (g + 1) * 256 + lane;
      n0 = pb[base]; n1 = pb[base + 64]; n2 = pb[base + 128]; n3 = pb[base + 192];
    }
    KPROC(a0, g*4+0) KPROC(a1, g*4+1) KPROC(a2, g*4+2) KPROC(a3, g*4+3)
    a0 = n0; a1 = n1; a2 = n2; a3 = n3;
  }
#undef KPROC

  if (lane < KNN) knn_idx[(size_t)q * KNN + lane] = (int)kidx;
}

// ---------------- main kernel v3: folded gamma, low register pressure ----------
// gamma = uA_i - uB_j + Wg@delta ; alpha = uC_j + delta
__global__ void __launch_bounds__(256, 2)
k_main3(const float* __restrict__ xyz,
        const float* __restrict__ feat,
        const int* __restrict__ knn_idx,
        const float* __restrict__ uA, const float* __restrict__ uB, const float* __restrict__ uC,
        const float4* __restrict__ weff,
        const float* __restrict__ Wg,
        const float* __restrict__ W2g, const float* __restrict__ b2g,
        float* __restrict__ out)
{
  __shared__ float4 sWg4[64 * 16];    // Wg row-major float4 chunks, 16KB
  __shared__ float  sW2[64 * 65];     // W2 +1-padded rows, 16.25KB
  __shared__ float4 sWeff[64];
  __shared__ float  sB2[64];

  const int tid = threadIdx.x;
  {
    const float4* wg4 = (const float4*)Wg;
    #pragma unroll
    for (int it = 0; it < 4; ++it) sWg4[it*256 + tid] = wg4[it*256 + tid];
    #pragma unroll
    for (int it = 0; it < 16; ++it) {
      int e = it*256 + tid;
      sW2[(e >> 6)*65 + (e & 63)] = W2g[e];
    }
    if (tid < 64) { sB2[tid] = b2g[tid]; sWeff[tid] = weff[tid]; }
  }
  __syncthreads();

  const int lane  = tid & 63;
  const int kslot = lane & 15;
  const int point = blockIdx.x * 16 + (tid >> 6) * 4 + (lane >> 4);
  const int b     = point >> 13;
  const int i     = point & (NP - 1);
  const size_t irow = (size_t)point * D;

  const int j = knn_idx[(size_t)blockIdx.x * 256 + tid];
  const size_t jrow = ((size_t)(b * NP + j)) * D;

  const float* xb = xyz + (size_t)b * NP * 3;
  const float dx = xb[i*3+0] - xb[j*3+0];
  const float dy = xb[i*3+1] - xb[j*3+1];
  const float dz = xb[i*3+2] - xb[j*3+2];

  // ---- gamma init: uA_i - uB_j (issue loads early) ----
  float gamma[64];
  {
    const float4* ua = (const float4*)(uA + irow);
    const float4* ub = (const float4*)(uB + jrow);
    #pragma unroll
    for (int cc = 0; cc < 16; ++cc) {
      float4 a = ua[cc];
      float4 v = ub[cc];
      gamma[cc*4+0] = a.x - v.x; gamma[cc*4+1] = a.y - v.y;
      gamma[cc*4+2] = a.z - v.z; gamma[cc*4+3] = a.w - v.w;
    }
  }

  // ---- delta = relu(Weff @ diff + beff) ----
  float delta[64];
  #pragma unroll
  for (int c = 0; c < 64; ++c) {
    float4 wf = sWeff[c];               // wave-uniform broadcast
    float t = fmaf(wf.z, dz, fmaf(wf.y, dy, fmaf(wf.x, dx, wf.w)));
    delta[c] = fmaxf(t, 0.f);
  }

  // ---- gamma += Wg @ delta (weights uniform from LDS) ----
  #pragma unroll
  for (int og = 0; og < 16; ++og) {
    float g0 = gamma[og*4+0], g1 = gamma[og*4+1], g2 = gamma[og*4+2], g3 = gamma[og*4+3];
    #pragma unroll
    for (int c4 = 0; c4 < 16; ++c4) {
      float4 w0 = sWg4[(og*4+0)*16 + c4];
      float4 w1 = sWg4[(og*4+1)*16 + c4];
      float4 w2 = sWg4[(og*4+2)*16 + c4];
      float4 w3 = sWg4[(og*4+3)*16 + c4];
      g0 = fmaf(w0.x, delta[c4*4+0], g0); g0 = fmaf(w0.y, delta[c4*4+1], g0);
      g0 = fmaf(w0.z, delta[c4*4+2], g0); g0 = fmaf(w0.w, delta[c4*4+3], g0);
      g1 = fmaf(w1.x, delta[c4*4+0], g1); g1 = fmaf(w1.y, delta[c4*4+1], g1);
      g1 = fmaf(w1.z, delta[c4*4+2], g1); g1 = fmaf(w1.w, delta[c4*4+3], g1);
      g2 = fmaf(w2.x, delta[c4*4+0], g2); g2 = fmaf(w2.y, delta[c4*4+1], g2);
      g2 = fmaf(w2.z, delta[c4*4+2], g2); g2 = fmaf(w2.w, delta[c4*4+3], g2);
      g3 = fmaf(w3.x, delta[c4*4+0], g3); g3 = fmaf(w3.y, delta[c4*4+1], g3);
      g3 = fmaf(w3.z, delta[c4*4+2], g3); g3 = fmaf(w3.w, delta[c4*4+3], g3);
    }
    gamma[og*4+0] = g0; gamma[og*4+1] = g1; gamma[og*4+2] = g2; gamma[og*4+3] = g3;
  }

  // ---- lane-local softmax over 64 channels ----
  float m0 = gamma[0], m1 = gamma[1], m2 = gamma[2], m3 = gamma[3];
  #pragma unroll
  for (int c = 4; c < 64; c += 4) {
    m0 = fmaxf(m0, gamma[c+0]); m1 = fmaxf(m1, gamma[c+1]);
    m2 = fmaxf(m2, gamma[c+2]); m3 = fmaxf(m3, gamma[c+3]);
  }
  const float m = fmaxf(fmaxf(m0, m1), fmaxf(m2, m3));
  float s0 = 0.f, s1 = 0.f, s2 = 0.f, s3 = 0.f;
  #pragma unroll
  for (int c = 0; c < 64; c += 4) {
    gamma[c+0] = __expf(gamma[c+0] - m); s0 += gamma[c+0];
    gamma[c+1] = __expf(gamma[c+1] - m); s1 += gamma[c+1];
    gamma[c+2] = __expf(gamma[c+2] - m); s2 += gamma[c+2];
    gamma[c+3] = __expf(gamma[c+3] - m); s3 += gamma[c+3];
  }
  const float inv = 1.0f / ((s0 + s1) + (s2 + s3));

  // ---- alpha = uC_j + delta; acc over K (reduce across 16 kslot lanes) ----
  {
    const float4* uc = (const float4*)(uC + jrow);
    #pragma unroll
    for (int cc = 0; cc < 16; ++cc) {
      float4 av = uc[cc];
      float avv[4] = {av.x, av.y, av.z, av.w};
      #pragma unroll
      for (int r = 0; r < 4; ++r) {
        const int c = cc*4 + r;
        float v = gamma[c] * inv * (avv[r] + delta[c]);
        v += __shfl_xor(v, 1, 64);
        v += __shfl_xor(v, 2, 64);
        v += __shfl_xor(v, 4, 64);
        v += __shfl_xor(v, 8, 64);
        gamma[c] = v;                   // per-point acc, replicated in 16 lanes
      }
    }
  }

  // ---- epilogue: out = acc @ W2^T + b2 + feat; lane kslot does 4 channels ----
  const int oc = kslot * 4;
  float o0 = sB2[oc+0], o1 = sB2[oc+1], o2 = sB2[oc+2], o3 = sB2[oc+3];
  #pragma unroll
  for (int c = 0; c < 64; ++c) {
    o0 = fmaf(sW2[(oc+0)*65 + c], gamma[c], o0);
    o1 = fmaf(sW2[(oc+1)*65 + c], gamma[c], o1);
    o2 = fmaf(sW2[(oc+2)*65 + c], gamma[c], o2);
    o3 = fmaf(sW2[(oc+3)*65 + c], gamma[c], o3);
  }
  float4 fv = *(const float4*)(feat + irow + oc);
  *(float4*)(out + irow + oc) = make_float4(o0 + fv.x, o1 + fv.y, o2 + fv.z, o3 + fv.w);
}

extern "C" void kernel_launch(void* const* d_in, const int* in_sizes, int n_in,
                              void* d_out, int out_size, void* d_ws, size_t ws_size,
                              hipStream_t stream) {
  const float* xyz  = (const float*)d_in[0];
  const float* feat = (const float*)d_in[1];
  // d_in[2] = k (int32) == 16, compile-time constant here
  const float* W1   = (const float*)d_in[3];
  const float* b1   = (const float*)d_in[4];
  const float* Wphi = (const float*)d_in[5];
  const float* bphi = (const float*)d_in[6];
  const float* Wpsi = (const float*)d_in[7];
  const float* bpsi = (const float*)d_in[8];
  const float* Wal  = (const float*)d_in[9];
  const float* bal  = (const float*)d_in[10];
  const float* Wg   = (const float*)d_in[11];
  const float* bg   = (const float*)d_in[12];
  const float* Wd1  = (const float*)d_in[13];
  const float* bd1  = (const float*)d_in[14];
  const float* Wd2  = (const float*)d_in[15];
  const float* bd2  = (const float*)d_in[16];
  const float* W2   = (const float*)d_in[17];
  const float* b2   = (const float*)d_in[18];

  float* out = (float*)d_out;

  // workspace layout (f32 words): uA | uB | uC | knn_idx | pts4 | weff | folds
  const size_t NPT = (size_t)NB * NP;     // 16384
  float* uA = (float*)d_ws;
  float* uB = uA + NPT * D;
  float* uC = uB + NPT * D;
  int* knn_idx = (int*)(uC + NPT * D);
  float4* pts4 = (float4*)(knn_idx + NPT * KNN);
  float4* weff = pts4 + NPT;
  float* Af  = (float*)(weff + 64);
  float* dAv = Af + 4096;
  float* Bf  = dAv + 64;
  float* dBv = Bf + 4096;
  float* Cf  = dBv + 64;
  float* dCv = Cf + 4096;

  // output 0: points_xyz passthrough (f32)
  hipMemcpyAsync(d_out, d_in[0], NPT * 3 * sizeof(float),
                 hipMemcpyDeviceToDevice, stream);

  k_prep<<<NPT / 256, 256, 0, stream>>>(xyz, pts4);
  k_fold<<<1, 64, 0, stream>>>(Wd1, bd1, Wd2, bd2, weff);
  k_fold2<<<3, 256, 0, stream>>>(Wg, bg, Wphi, bphi, Wpsi, bpsi, Wal, bal, W1, b1,
                                 Af, dAv, Bf, dBv, Cf, dCv);
  k_transform2<<<NPT / 32, 256, 0, stream>>>(feat, Af, dAv, Bf, dBv, Cf, dCv, uA, uB, uC);
  k_knn5<<<NPT / 4, 256, 0, stream>>>(pts4, knn_idx);
  k_main3<<<NPT / 16, 256, 0, stream>>>(xyz, feat, knn_idx, uA, uB, uC, weff,
                                        Wg, W2, b2, out + NPT * 3);
}